// Round 15
// baseline (77.881 us; speedup 1.0000x reference)
//
#include <hip/hip_runtime.h>
#include <hip/hip_bf16.h>

// Problem: B=4, C=256, N=4096 (16^3).
// out[b,c,n] = sum_m relu(cos(x_n,x_m))^2 * (W x + b)[c,m]
// xn = x/||x|| (bf16) -> S = xn^T xn, P = relu(S)^2,
// T[c,m] = nrm[m]*(W xn)[c,m] + b[c],  out = T * P^T.
//
// r15: k_prep/k_tgemm byte-identical to r14 (proven). k_fused: 2-tile
// phases (r10's proven cadence) + 8-slot ring + consumer 3-buffer tb
// rotation so EVERY global load is consumed strictly in a LATER phase
// (>=1 phase + 1 MFMA cluster of cover, ~1400cyc) — removes r11/r14's
// same-phase reload consumption (~600cyc cover) that stalled on L2 queuing.

typedef unsigned short u16;
typedef __attribute__((ext_vector_type(8))) short short8;   // 8 bf16 = 4 VGPRs
typedef __attribute__((ext_vector_type(4))) float f32x4;

#define MFMA16(a, b, c) __builtin_amdgcn_mfma_f32_16x16x32_bf16((a), (b), (c), 0, 0, 0)

__device__ __forceinline__ u16 f2bf(float f) {
    union { float f; unsigned u; } v; v.f = f;
    unsigned u = v.u;
    u += 0x7fffu + ((u >> 16) & 1u);   // RNE
    return (u16)(u >> 16);
}

__device__ __forceinline__ unsigned cvtpk(float lo, float hi) {   // 2x f32 -> packed bf16 (RNE)
    unsigned r;
    asm("v_cvt_pk_bf16_f32 %0, %1, %2" : "=v"(r) : "v"(lo), "v"(hi));
    return r;
}

// ------- K1: norm + fragment-major transpose + W-fragment convert ------------
__global__ __launch_bounds__(256) void k_prep(const float* __restrict__ x,
                                              const float* __restrict__ W,
                                              u16* __restrict__ xff,
                                              u16* __restrict__ Wf,
                                              float* __restrict__ nrm) {
    __shared__ float xs[256][65];     // 65 pad: conflict-free col reads
    __shared__ float part[4][64];
    __shared__ float rs_s[64];
    int bid = blockIdx.x;
    int b = bid >> 6, nt = bid & 63, n0 = nt << 6;
    int tid = threadIdx.x;

    if (bid < 32) {       // W fragment conversion (8192 chunks total)
        int q = (bid << 8) + tid;
        int lane = q & 63, kc = (q >> 6) & 7, ci = (q >> 9) & 3, wq = q >> 11;
        int row = (wq << 6) + (ci << 4) + (lane & 15);
        int col = (kc << 5) + ((lane >> 4) << 3);
        const float* wp = W + row * 256 + col;
        u16 tmp[8];
#pragma unroll
        for (int j = 0; j < 8; ++j) tmp[j] = f2bf(wp[j]);
        *(short8*)(Wf + ((size_t)q << 3)) = *(const short8*)tmp;
    }

    int rowg = tid >> 4, l16 = tid & 15;
    const float* xb = x + ((size_t)b << 20) + n0;
#pragma unroll
    for (int s = 0; s < 16; ++s) {
        int row = (s << 4) + rowg;                // c index
        float4 v = *(const float4*)(xb + (size_t)row * 4096 + (l16 << 2));
        xs[row][(l16 << 2) + 0] = v.x;
        xs[row][(l16 << 2) + 1] = v.y;
        xs[row][(l16 << 2) + 2] = v.z;
        xs[row][(l16 << 2) + 3] = v.w;
    }
    __syncthreads();
    int q2 = tid >> 6, nl = tid & 63;
    float ss = 0.f;
#pragma unroll 16
    for (int c = 0; c < 64; ++c) {
        float v = xs[(q2 << 6) + c][nl];
        ss += v * v;
    }
    part[q2][nl] = ss;
    __syncthreads();
    if (tid < 64) {
        float t = part[0][tid] + part[1][tid] + part[2][tid] + part[3][tid];
        float nr = sqrtf(t);
        nrm[(b << 12) + n0 + tid] = nr;
        rs_s[tid] = 1.0f / fmaxf(nr, 1e-8f);
    }
    __syncthreads();

    u16* xo = xff + ((size_t)b << 20) + ((size_t)nt << 14);
    int lane = tid & 63;
#pragma unroll
    for (int s = 0; s < 8; ++s) {
        int w2 = (s << 2) + (tid >> 6);           // 0..31
        int tl = ((w2 & 3) << 4) + (tid & 15);    // local row 0..63
        int c8 = ((w2 >> 2) << 2) + ((tid >> 4) & 3);   // col-chunk 0..31
        float rsv = rs_s[tl];
        u16 tmp[8];
#pragma unroll
        for (int j = 0; j < 8; ++j)
            tmp[j] = f2bf(xs[(c8 << 3) + j][tl] * rsv);
        int chunk = ((tl >> 4) << 3) + (c8 >> 2); // rt*8 + kc
        *(short8*)(xo + (chunk << 9) + (lane << 3)) = *(const short8*)tmp;
    }
}

// ---- K2: T = nrm*(W xn) + bias, output fragment-major tbf -------------------
__global__ __launch_bounds__(256) void k_tgemm(const u16* __restrict__ Wf,
                                               const u16* __restrict__ xff,
                                               const float* __restrict__ bias,
                                               const float* __restrict__ nrm,
                                               u16* __restrict__ tbf) {
    __shared__ u16 lds_t[256][72];
    int bid = blockIdx.x;
    int b = bid >> 6, mt = bid & 63;
    const u16* xf_t = xff + ((size_t)b << 20) + ((size_t)mt << 14);
    int tid = threadIdx.x, wid = tid >> 6, lane = tid & 63, lg = lane >> 4, lr = lane & 15;

    f32x4 zero = {0.f, 0.f, 0.f, 0.f};
    f32x4 acc[4][4];
#pragma unroll
    for (int ci = 0; ci < 4; ++ci)
#pragma unroll
        for (int mj = 0; mj < 4; ++mj) acc[ci][mj] = zero;

#pragma unroll
    for (int kc = 0; kc < 8; ++kc) {
        short8 afr[4], bfr[4];
#pragma unroll
        for (int ci = 0; ci < 4; ++ci)
            afr[ci] = *(const short8*)(Wf + ((size_t)((((wid << 2) + ci) << 3) + kc) << 9)
                                       + (lane << 3));
#pragma unroll
        for (int mj = 0; mj < 4; ++mj)
            bfr[mj] = *(const short8*)(xf_t + ((size_t)(((mj << 3) + kc)) << 9)
                                       + (lane << 3));
#pragma unroll
        for (int ci = 0; ci < 4; ++ci)
#pragma unroll
            for (int mj = 0; mj < 4; ++mj)
                acc[ci][mj] = MFMA16(afr[ci], bfr[mj], acc[ci][mj]);
    }
    float nv[4];
#pragma unroll
    for (int mj = 0; mj < 4; ++mj)
        nv[mj] = nrm[(b << 12) + (mt << 6) + (mj << 4) + lr];
#pragma unroll
    for (int ci = 0; ci < 4; ++ci) {
#pragma unroll
        for (int r = 0; r < 4; ++r) {
            int c = (wid << 6) + (ci << 4) + (lg << 2) + r;
            float bv = bias[c];
#pragma unroll
            for (int mj = 0; mj < 4; ++mj)
                lds_t[c][(mj << 4) + lr] = f2bf(acc[ci][mj][r] * nv[mj] + bv);
        }
    }
    __syncthreads();
    u16* to = tbf + ((size_t)b << 20) + ((size_t)mt << 14);
#pragma unroll
    for (int s = 0; s < 8; ++s) {
        int w2 = (s << 2) + (tid >> 6);
        int cq = w2 >> 3, ci2 = (w2 >> 1) & 3, k2 = w2 & 1;
        short8 v = *(const short8*)(&lds_t[(cq << 6) + (ci2 << 4) + lr][(k2 << 5) + (lg << 3)]);
        *(short8*)(to + (w2 << 9) + (lane << 3)) = v;
    }
}

// ---------------- K3: fused  O[:,ntile] = T * P^T  --------------------------
// 256 blocks (1/CU), 512 threads (8 waves), producer/consumer split.
// 2-tile phases, 33 matched barriers, 8-slot swizzled P-ring (slot=tile&7).
// Producer: tiles 2p+2,2p+3 in phase p; bfr 2-deep (loads consumed next
// phase). Consumer: tiles 2p,2p+1 in phase p; tb 3-buffer rotation (A,B,C,
// period 3 phases) so each tb load is consumed >=1 full phase later.
// pfr double-buffered per phase. No load is consumed in its issuing phase.
__global__ __launch_bounds__(512) void k_fused(const u16* __restrict__ xff,
                                               const u16* __restrict__ tbf,
                                               float* __restrict__ out) {
    __shared__ __align__(16) u16 lds_p[8][4096];   // P ring, 8 x 8KB, swizzled

#define PBYTE(row, col) ((((row) << 7) + ((col) << 1)) ^ (((row) & 7) << 4))
#define BAR() do { asm volatile("s_waitcnt lgkmcnt(0)" ::: "memory");              \
    __builtin_amdgcn_sched_barrier(0); __builtin_amdgcn_s_barrier();               \
    __builtin_amdgcn_sched_barrier(0); } while (0)
#define TS 16384   // u16 per 64-m tile of xff/tbf

    int bid = blockIdx.x;
    int xcd = bid & 7, grp = bid >> 3;
    int batch = xcd >> 1;
    int nt = grp + 32 * (xcd & 1);
    int n0 = nt << 6;

    const u16* xf_b = xff + ((size_t)batch << 20);
    const u16* tb_f = tbf + ((size_t)batch << 20);
    float* out_b = out + ((size_t)batch << 20);

    int tid = threadIdx.x;
    int wid = tid >> 6, lane = tid & 63, lg = lane >> 4, lr = lane & 15;
    int lane8 = lane << 3;
    f32x4 zero = {0.f, 0.f, 0.f, 0.f};
    char* pbase = (char*)&lds_p[0][0];

    if (wid < 4) {
        // ================= producer: S / P =================
        int tc = wid;
        int colw = (tc << 4) + lr;
        short8 afrag[4][8];
#pragma unroll
        for (int rt = 0; rt < 4; ++rt)
#pragma unroll
            for (int kc = 0; kc < 8; ++kc)
                afrag[rt][kc] = *(const short8*)(xf_b
                    + ((size_t)((((nt << 2) + rt) << 3) + kc) << 9) + lane8);
        const u16* bb = xf_b + ((size_t)(tc << 3) << 9);   // uniform base
        short8 bfrA[8], bfrB[8];

#define RLDB(BUF, OFF)                                                                     \
        { _Pragma("unroll")                                                                \
          for (int kc = 0; kc < 8; ++kc)                                                   \
              BUF[kc] = *(const short8*)(bb + (OFF) + (kc << 9) + lane8); }

#define SCOMP(BUF, SLOT)                                                                   \
    {                                                                                      \
        f32x4 sac[4];                                                                      \
        _Pragma("unroll") for (int c = 0; c < 4; ++c) sac[c] = zero;                       \
        __builtin_amdgcn_s_setprio(1);                                                     \
        _Pragma("unroll")                                                                  \
        for (int kc = 0; kc < 8; ++kc) {                                                   \
            sac[0] = MFMA16(afrag[0][kc], BUF[kc], sac[0]);                                \
            sac[1] = MFMA16(afrag[1][kc], BUF[kc], sac[1]);                                \
            sac[2] = MFMA16(afrag[2][kc], BUF[kc], sac[2]);                                \
            sac[3] = MFMA16(afrag[3][kc], BUF[kc], sac[3]);                                \
        }                                                                                  \
        __builtin_amdgcn_s_setprio(0);                                                     \
        char* pd = pbase + ((SLOT) << 13);                                                 \
        _Pragma("unroll")                                                                  \
        for (int c = 0; c < 4; ++c) {                                                      \
            float q0 = fmaxf(sac[c][0], 0.f); q0 *= q0;                                    \
            float q1 = fmaxf(sac[c][1], 0.f); q1 *= q1;                                    \
            float q2 = fmaxf(sac[c][2], 0.f); q2 *= q2;                                    \
            float q3 = fmaxf(sac[c][3], 0.f); q3 *= q3;                                    \
            unsigned d01 = cvtpk(q0, q1);                                                  \
            unsigned d23 = cvtpk(q2, q3);                                                  \
            int rw = (lg << 2) + (c << 4);                                                 \
            *(u16*)(pd + PBYTE(rw, colw)) = (u16)d01;                                      \
            *(u16*)(pd + PBYTE(rw + 1, colw)) = (u16)(d01 >> 16);                          \
            *(u16*)(pd + PBYTE(rw + 2, colw)) = (u16)d23;                                  \
            *(u16*)(pd + PBYTE(rw + 3, colw)) = (u16)(d23 >> 16);                          \
        }                                                                                  \
    }

        // prologue: tiles 0,1 -> slots 0,1; preload tiles 2,3
        RLDB(bfrA, 0);
        RLDB(bfrB, TS);
        SCOMP(bfrA, 0); RLDB(bfrA, 2 * TS);
        SCOMP(bfrB, 1); RLDB(bfrB, 3 * TS);
        BAR();
        // 7 groups of 4 phases (8 tiles each): tiles 8j+2 .. 8j+9, bb = 8j
        for (int g7 = 0; g7 < 7; ++g7) {
            SCOMP(bfrA, 2); RLDB(bfrA, 4 * TS);
            SCOMP(bfrB, 3); RLDB(bfrB, 5 * TS);  BAR();
            SCOMP(bfrA, 4); RLDB(bfrA, 6 * TS);
            SCOMP(bfrB, 5); RLDB(bfrB, 7 * TS);  BAR();
            SCOMP(bfrA, 6); RLDB(bfrA, 8 * TS);
            SCOMP(bfrB, 7); RLDB(bfrB, 9 * TS);  BAR();
            SCOMP(bfrA, 0); RLDB(bfrA, 10 * TS);
            SCOMP(bfrB, 1); RLDB(bfrB, 11 * TS); BAR();
            bb += 8 * TS;
        }
        // tail: bb = 56. phases 28..31
        SCOMP(bfrA, 2); RLDB(bfrA, 4 * TS);    // tiles 58,59; load 60,61
        SCOMP(bfrB, 3); RLDB(bfrB, 5 * TS);  BAR();
        SCOMP(bfrA, 4); RLDB(bfrA, 6 * TS);    // tiles 60,61; load 62,63
        SCOMP(bfrB, 5); RLDB(bfrB, 7 * TS);  BAR();
        SCOMP(bfrA, 6);                        // tiles 62,63
        SCOMP(bfrB, 7);  BAR();
        BAR();                                 // consumer's last phase
#undef SCOMP
#undef RLDB
    } else {
        // ================= consumer: O += T * P^T =================
        int cq = wid - 4;
        const u16* tbse = tb_f + ((size_t)(cq << 3) << 9);   // uniform base
        short8 tbcA[4][2], tbcB[4][2], tbcC[4][2];

#define RLDT(TB, OFF)                                                                      \
        { _Pragma("unroll")                                                                \
          for (int ci = 0; ci < 4; ++ci) {                                                 \
              _Pragma("unroll")                                                            \
              for (int k2 = 0; k2 < 2; ++k2)                                               \
                  TB[ci][k2] = *(const short8*)(tbse + (OFF)                               \
                                                + ((((ci << 1) + k2)) << 9) + lane8); } }

#define RDP(PFR, SLOT)                                                                     \
    {                                                                                      \
        char* pc = pbase + ((SLOT) << 13);                                                 \
        _Pragma("unroll")                                                                  \
        for (int nj = 0; nj < 4; ++nj) {                                                   \
            PFR[nj][0] = *(const short8*)(pc + PBYTE((nj << 4) + lr, (lg << 3)));          \
            PFR[nj][1] = *(const short8*)(pc + PBYTE((nj << 4) + lr, 32 + (lg << 3)));     \
        }                                                                                  \
    }

#define OMMA(TC, PFR)                                                                      \
    {                                                                                      \
        __builtin_amdgcn_s_setprio(1);                                                     \
        _Pragma("unroll")                                                                  \
        for (int ci = 0; ci < 4; ++ci) {                                                   \
            _Pragma("unroll")                                                              \
            for (int nj = 0; nj < 4; ++nj) {                                               \
                oacc[ci][nj] = MFMA16(TC[ci][0], PFR[nj][0], oacc[ci][nj]);                \
                oacc[ci][nj] = MFMA16(TC[ci][1], PFR[nj][1], oacc[ci][nj]);                \
            }                                                                              \
        }                                                                                  \
        __builtin_amdgcn_s_setprio(0);                                                     \
    }

        // 3-phase group (6 tiles, base g = tbse's tile). Entry bufs:
        // {A=g, B=g+1, C=g+2}. Each load consumed >= 1 phase later.
#define CGRP(s0, s1, s2, s3, s4, s5)                                                       \
    {                                                                                      \
        short8 pfA[4][2], pfB[4][2];                                                       \
        RDP(pfA, s0); RDP(pfB, s1);                                                        \
        OMMA(tbcA, pfA); RLDT(tbcA, 3 * TS);                                               \
        OMMA(tbcB, pfB); RLDT(tbcB, 4 * TS);                                               \
        BAR();                                                                             \
        RDP(pfA, s2); RDP(pfB, s3);                                                        \
        OMMA(tbcC, pfA); RLDT(tbcC, 5 * TS);                                               \
        OMMA(tbcA, pfB); RLDT(tbcA, 6 * TS);                                               \
        BAR();                                                                             \
        RDP(pfA, s4); RDP(pfB, s5);                                                        \
        OMMA(tbcB, pfA); RLDT(tbcB, 7 * TS);                                               \
        OMMA(tbcC, pfB); RLDT(tbcC, 8 * TS);                                               \
        BAR();                                                                             \
        tbse += 6 * TS;                                                                    \
    }

        // prologue: 3-deep tb preload (tiles 0,1,2)
        RLDT(tbcA, 0);
        RLDT(tbcB, TS);
        RLDT(tbcC, 2 * TS);
        f32x4 oacc[4][4];
#pragma unroll
        for (int ci = 0; ci < 4; ++ci)
#pragma unroll
            for (int nj = 0; nj < 4; ++nj) oacc[ci][nj] = zero;
        BAR();

        // 10 groups: tiles 0..59. Slot patterns cycle with period 4 groups.
        for (int pp = 0; pp < 2; ++pp) {
            CGRP(0, 1, 2, 3, 4, 5);
            CGRP(6, 7, 0, 1, 2, 3);
            CGRP(4, 5, 6, 7, 0, 1);
            CGRP(2, 3, 4, 5, 6, 7);
        }
        CGRP(0, 1, 2, 3, 4, 5);
        CGRP(6, 7, 0, 1, 2, 3);
        // tail: bufs {A=60, B=61, C=62}, tbse at tile 60. phases 30,31.
        {
            short8 pfA[4][2], pfB[4][2];
            RDP(pfA, 4); RDP(pfB, 5);
            OMMA(tbcA, pfA); RLDT(tbcA, 3 * TS);   // A <- tile 63
            OMMA(tbcB, pfB);
            BAR();
            RDP(pfA, 6); RDP(pfB, 7);
            OMMA(tbcC, pfA);
            OMMA(tbcA, pfB);
            BAR();
        }
#undef CGRP
#undef OMMA
#undef RDP
#undef RLDT

        // epilogue: write O fp32
#pragma unroll
        for (int ci = 0; ci < 4; ++ci) {
            int c = (cq << 6) + (ci << 4) + (lg << 2);
#pragma unroll
            for (int nj = 0; nj < 4; ++nj) {
                int n = n0 + (nj << 4) + lr;
                float* op = out_b + (size_t)c * 4096 + n;
#pragma unroll
                for (int r = 0; r < 4; ++r) op[(size_t)r * 4096] = oacc[ci][nj][r];
            }
        }
    }
#undef PBYTE
#undef BAR
#undef TS
}

extern "C" void kernel_launch(void* const* d_in, const int* in_sizes, int n_in,
                              void* d_out, int out_size, void* d_ws, size_t ws_size,
                              hipStream_t stream) {
    const float* x = (const float*)d_in[0];     // (4,256,16,16,16) fp32
    const float* W = (const float*)d_in[1];     // (256,256) fp32
    const float* bias = (const float*)d_in[2];  // (256,) fp32
    float* out = (float*)d_out;

    char* ws = (char*)d_ws;
    u16* xff = (u16*)ws;                                   // 8 MiB: xn fragment-major
    u16* tbf = (u16*)(ws + ((size_t)8 << 20));             // 8 MiB: T fragment-major
    u16* Wf = (u16*)(ws + ((size_t)16 << 20));             // 128 KiB: W fragment-major
    float* nrm = (float*)(ws + ((size_t)16 << 20) + (192u << 10));  // 64 KiB

    hipLaunchKernelGGL(k_prep, dim3(256), dim3(256), 0, stream, x, W, xff, Wf, nrm);
    hipLaunchKernelGGL(k_tgemm, dim3(256), dim3(256), 0, stream, Wf, xff, bias, nrm, tbf);
    hipLaunchKernelGGL(k_fused, dim3(256), dim3(512), 0, stream, xff, tbf, out);
}

// Round 16
// 76.226 us; speedup vs baseline: 1.0217x; 1.0217x over previous
//
#include <hip/hip_runtime.h>
#include <hip/hip_bf16.h>

// Problem: B=4, C=256, N=4096 (16^3).
// out[b,c,n] = sum_m relu(cos(x_n,x_m))^2 * (W x + b)[c,m]
// xn = x/||x|| (bf16) -> S = xn^T xn, P = relu(S)^2,
// T[c,m] = nrm[m]*(W xn)[c,m] + b[c],  out = T * P^T.
//
// FINAL (r16 = r14, proven 76.6us): fragment-major layouts (every k_fused
// in-loop load is base+lane*16B coalesced — the r7/r8 insight worth 2.7x),
// producer/consumer wave specialization with P-only swizzled LDS ring,
// 8-slot ring / 4-tile phases / one lgkm-only barrier per phase, cvt_pk
// P-pack, imm addressing, setprio (T5). 47% of dense MFMA peak; bounded by
// MFMA∥L2∥LDS co-binding at 2 waves/SIMD (register wall: 244/512 regs/SIMD
// per wave pair; 3rd wave impossible, async decoupling failed correctness).

typedef unsigned short u16;
typedef __attribute__((ext_vector_type(8))) short short8;   // 8 bf16 = 4 VGPRs
typedef __attribute__((ext_vector_type(4))) float f32x4;

#define MFMA16(a, b, c) __builtin_amdgcn_mfma_f32_16x16x32_bf16((a), (b), (c), 0, 0, 0)

__device__ __forceinline__ u16 f2bf(float f) {
    union { float f; unsigned u; } v; v.f = f;
    unsigned u = v.u;
    u += 0x7fffu + ((u >> 16) & 1u);   // RNE
    return (u16)(u >> 16);
}

__device__ __forceinline__ unsigned cvtpk(float lo, float hi) {   // 2x f32 -> packed bf16 (RNE)
    unsigned r;
    asm("v_cvt_pk_bf16_f32 %0, %1, %2" : "=v"(r) : "v"(lo), "v"(hi));
    return r;
}

// ------- K1: norm + fragment-major transpose + W-fragment convert ------------
__global__ __launch_bounds__(256) void k_prep(const float* __restrict__ x,
                                              const float* __restrict__ W,
                                              u16* __restrict__ xff,
                                              u16* __restrict__ Wf,
                                              float* __restrict__ nrm) {
    __shared__ float xs[256][65];     // 65 pad: conflict-free col reads
    __shared__ float part[4][64];
    __shared__ float rs_s[64];
    int bid = blockIdx.x;
    int b = bid >> 6, nt = bid & 63, n0 = nt << 6;
    int tid = threadIdx.x;

    if (bid < 32) {       // W fragment conversion (8192 chunks total)
        int q = (bid << 8) + tid;
        int lane = q & 63, kc = (q >> 6) & 7, ci = (q >> 9) & 3, wq = q >> 11;
        int row = (wq << 6) + (ci << 4) + (lane & 15);
        int col = (kc << 5) + ((lane >> 4) << 3);
        const float* wp = W + row * 256 + col;
        u16 tmp[8];
#pragma unroll
        for (int j = 0; j < 8; ++j) tmp[j] = f2bf(wp[j]);
        *(short8*)(Wf + ((size_t)q << 3)) = *(const short8*)tmp;
    }

    int rowg = tid >> 4, l16 = tid & 15;
    const float* xb = x + ((size_t)b << 20) + n0;
#pragma unroll
    for (int s = 0; s < 16; ++s) {
        int row = (s << 4) + rowg;                // c index
        float4 v = *(const float4*)(xb + (size_t)row * 4096 + (l16 << 2));
        xs[row][(l16 << 2) + 0] = v.x;
        xs[row][(l16 << 2) + 1] = v.y;
        xs[row][(l16 << 2) + 2] = v.z;
        xs[row][(l16 << 2) + 3] = v.w;
    }
    __syncthreads();
    int q2 = tid >> 6, nl = tid & 63;
    float ss = 0.f;
#pragma unroll 16
    for (int c = 0; c < 64; ++c) {
        float v = xs[(q2 << 6) + c][nl];
        ss += v * v;
    }
    part[q2][nl] = ss;
    __syncthreads();
    if (tid < 64) {
        float t = part[0][tid] + part[1][tid] + part[2][tid] + part[3][tid];
        float nr = sqrtf(t);
        nrm[(b << 12) + n0 + tid] = nr;
        rs_s[tid] = 1.0f / fmaxf(nr, 1e-8f);
    }
    __syncthreads();

    u16* xo = xff + ((size_t)b << 20) + ((size_t)nt << 14);
    int lane = tid & 63;
#pragma unroll
    for (int s = 0; s < 8; ++s) {
        int w2 = (s << 2) + (tid >> 6);           // 0..31
        int tl = ((w2 & 3) << 4) + (tid & 15);    // local row 0..63
        int c8 = ((w2 >> 2) << 2) + ((tid >> 4) & 3);   // col-chunk 0..31
        float rsv = rs_s[tl];
        u16 tmp[8];
#pragma unroll
        for (int j = 0; j < 8; ++j)
            tmp[j] = f2bf(xs[(c8 << 3) + j][tl] * rsv);
        int chunk = ((tl >> 4) << 3) + (c8 >> 2); // rt*8 + kc
        *(short8*)(xo + (chunk << 9) + (lane << 3)) = *(const short8*)tmp;
    }
}

// ---- K2: T = nrm*(W xn) + bias, output fragment-major tbf -------------------
__global__ __launch_bounds__(256) void k_tgemm(const u16* __restrict__ Wf,
                                               const u16* __restrict__ xff,
                                               const float* __restrict__ bias,
                                               const float* __restrict__ nrm,
                                               u16* __restrict__ tbf) {
    __shared__ u16 lds_t[256][72];
    int bid = blockIdx.x;
    int b = bid >> 6, mt = bid & 63;
    const u16* xf_t = xff + ((size_t)b << 20) + ((size_t)mt << 14);
    int tid = threadIdx.x, wid = tid >> 6, lane = tid & 63, lg = lane >> 4, lr = lane & 15;

    f32x4 zero = {0.f, 0.f, 0.f, 0.f};
    f32x4 acc[4][4];
#pragma unroll
    for (int ci = 0; ci < 4; ++ci)
#pragma unroll
        for (int mj = 0; mj < 4; ++mj) acc[ci][mj] = zero;

#pragma unroll
    for (int kc = 0; kc < 8; ++kc) {
        short8 afr[4], bfr[4];
#pragma unroll
        for (int ci = 0; ci < 4; ++ci)
            afr[ci] = *(const short8*)(Wf + ((size_t)((((wid << 2) + ci) << 3) + kc) << 9)
                                       + (lane << 3));
#pragma unroll
        for (int mj = 0; mj < 4; ++mj)
            bfr[mj] = *(const short8*)(xf_t + ((size_t)(((mj << 3) + kc)) << 9)
                                       + (lane << 3));
#pragma unroll
        for (int ci = 0; ci < 4; ++ci)
#pragma unroll
            for (int mj = 0; mj < 4; ++mj)
                acc[ci][mj] = MFMA16(afr[ci], bfr[mj], acc[ci][mj]);
    }
    float nv[4];
#pragma unroll
    for (int mj = 0; mj < 4; ++mj)
        nv[mj] = nrm[(b << 12) + (mt << 6) + (mj << 4) + lr];
#pragma unroll
    for (int ci = 0; ci < 4; ++ci) {
#pragma unroll
        for (int r = 0; r < 4; ++r) {
            int c = (wid << 6) + (ci << 4) + (lg << 2) + r;
            float bv = bias[c];
#pragma unroll
            for (int mj = 0; mj < 4; ++mj)
                lds_t[c][(mj << 4) + lr] = f2bf(acc[ci][mj][r] * nv[mj] + bv);
        }
    }
    __syncthreads();
    u16* to = tbf + ((size_t)b << 20) + ((size_t)mt << 14);
#pragma unroll
    for (int s = 0; s < 8; ++s) {
        int w2 = (s << 2) + (tid >> 6);
        int cq = w2 >> 3, ci2 = (w2 >> 1) & 3, k2 = w2 & 1;
        short8 v = *(const short8*)(&lds_t[(cq << 6) + (ci2 << 4) + lr][(k2 << 5) + (lg << 3)]);
        *(short8*)(to + (w2 << 9) + (lane << 3)) = v;
    }
}

// ---------------- K3: fused  O[:,ntile] = T * P^T  --------------------------
// 256 blocks (1/CU), 512 threads (8 waves), producer/consumer split.
// 8-slot swizzled P-ring (slot = tile&7), 4-tile phases; phase bodies fully
// unrolled (compile-time slots, imm global offsets); pfr double-buffered so
// slot j+1's LDS reads issue under OMMA j. Reloads +2/+3 consumed same
// phase (1-cluster cover), +4/+5 next phase. One lgkm-only barrier/phase.
__global__ __launch_bounds__(512) void k_fused(const u16* __restrict__ xff,
                                               const u16* __restrict__ tbf,
                                               float* __restrict__ out) {
    __shared__ __align__(16) u16 lds_p[8][4096];   // P ring, 8 x 8KB, swizzled

#define PBYTE(row, col) ((((row) << 7) + ((col) << 1)) ^ (((row) & 7) << 4))
#define BAR() do { asm volatile("s_waitcnt lgkmcnt(0)" ::: "memory");              \
    __builtin_amdgcn_sched_barrier(0); __builtin_amdgcn_s_barrier();               \
    __builtin_amdgcn_sched_barrier(0); } while (0)

    int bid = blockIdx.x;
    int xcd = bid & 7, grp = bid >> 3;
    int batch = xcd >> 1;
    int nt = grp + 32 * (xcd & 1);
    int n0 = nt << 6;

    const u16* xf_b = xff + ((size_t)batch << 20);
    const u16* tb_f = tbf + ((size_t)batch << 20);
    float* out_b = out + ((size_t)batch << 20);

    int tid = threadIdx.x;
    int wid = tid >> 6, lane = tid & 63, lg = lane >> 4, lr = lane & 15;
    int lane8 = lane << 3;
    f32x4 zero = {0.f, 0.f, 0.f, 0.f};
    char* pbase = (char*)&lds_p[0][0];

    if (wid < 4) {
        // ================= producer: S / P =================
        int tc = wid;
        int colw = (tc << 4) + lr;
        short8 afrag[4][8];
#pragma unroll
        for (int rt = 0; rt < 4; ++rt)
#pragma unroll
            for (int kc = 0; kc < 8; ++kc)
                afrag[rt][kc] = *(const short8*)(xf_b
                    + ((size_t)((((nt << 2) + rt) << 3) + kc) << 9) + lane8);
        const u16* bb = xf_b + ((size_t)(tc << 3) << 9);   // uniform base; tile=16384 u16
        short8 bfrA[8], bfrB[8];

#define RLDB(BUF, OFF)                                                                     \
        { _Pragma("unroll")                                                                \
          for (int kc = 0; kc < 8; ++kc)                                                   \
              BUF[kc] = *(const short8*)(bb + (OFF) + (kc << 9) + lane8); }

#define SCOMP(BUF, SLOT)                                                                   \
    {                                                                                      \
        f32x4 sac[4];                                                                      \
        _Pragma("unroll") for (int c = 0; c < 4; ++c) sac[c] = zero;                       \
        __builtin_amdgcn_s_setprio(1);                                                     \
        _Pragma("unroll")                                                                  \
        for (int kc = 0; kc < 8; ++kc) {                                                   \
            sac[0] = MFMA16(afrag[0][kc], BUF[kc], sac[0]);                                \
            sac[1] = MFMA16(afrag[1][kc], BUF[kc], sac[1]);                                \
            sac[2] = MFMA16(afrag[2][kc], BUF[kc], sac[2]);                                \
            sac[3] = MFMA16(afrag[3][kc], BUF[kc], sac[3]);                                \
        }                                                                                  \
        __builtin_amdgcn_s_setprio(0);                                                     \
        char* pd = pbase + ((SLOT) << 13);                                                 \
        _Pragma("unroll")                                                                  \
        for (int c = 0; c < 4; ++c) {                                                      \
            float q0 = fmaxf(sac[c][0], 0.f); q0 *= q0;                                    \
            float q1 = fmaxf(sac[c][1], 0.f); q1 *= q1;                                    \
            float q2 = fmaxf(sac[c][2], 0.f); q2 *= q2;                                    \
            float q3 = fmaxf(sac[c][3], 0.f); q3 *= q3;                                    \
            unsigned d01 = cvtpk(q0, q1);                                                  \
            unsigned d23 = cvtpk(q2, q3);                                                  \
            int rw = (lg << 2) + (c << 4);                                                 \
            *(u16*)(pd + PBYTE(rw, colw)) = (u16)d01;                                      \
            *(u16*)(pd + PBYTE(rw + 1, colw)) = (u16)(d01 >> 16);                          \
            *(u16*)(pd + PBYTE(rw + 2, colw)) = (u16)d23;                                  \
            *(u16*)(pd + PBYTE(rw + 3, colw)) = (u16)(d23 >> 16);                          \
        }                                                                                  \
    }

        // producer phase body: tiles t..t+3 (t = bb's tile) -> slots S0..S3;
        // reloads t+2,t+3 (consumed this phase) and t+4,t+5 (next phase).
#define PPH_FULL(S0, S1, S2, S3)                                                           \
        SCOMP(bfrA, S0); RLDB(bfrA, 2 * 16384);                                            \
        SCOMP(bfrB, S1); RLDB(bfrB, 3 * 16384);                                            \
        SCOMP(bfrA, S2); RLDB(bfrA, 4 * 16384);                                            \
        SCOMP(bfrB, S3); RLDB(bfrB, 5 * 16384);                                            \
        bb += 4 * 16384; BAR();

        // prologue: tiles 0-3 -> slots 0-3 (PPH pattern + initial loads)
        RLDB(bfrA, 0);
        RLDB(bfrB, 16384);
        PPH_FULL(0, 1, 2, 3);
        // phases k=0..13: 7 pairs; k even -> slots 4-7, odd -> 0-3
        for (int pp = 0; pp < 7; ++pp) {
            PPH_FULL(4, 5, 6, 7);
            PPH_FULL(0, 1, 2, 3);
        }
        // phase 14: tiles 60-63 -> slots 4-7; reload only 62,63
        SCOMP(bfrA, 4); RLDB(bfrA, 2 * 16384);
        SCOMP(bfrB, 5); RLDB(bfrB, 3 * 16384);
        SCOMP(bfrA, 6);
        SCOMP(bfrB, 7);
        BAR();
        // phase 15: consumers eat 60-63
        BAR();
#undef PPH_FULL
#undef SCOMP
#undef RLDB
    } else {
        // ================= consumer: O += T * P^T =================
        int cq = wid - 4;
        const u16* tbse = tb_f + ((size_t)(cq << 3) << 9);   // uniform base
        short8 tbcA[4][2], tbcB[4][2];

#define RLDT(TB, OFF)                                                                      \
        { _Pragma("unroll")                                                                \
          for (int ci = 0; ci < 4; ++ci) {                                                 \
              _Pragma("unroll")                                                            \
              for (int k2 = 0; k2 < 2; ++k2)                                               \
                  TB[ci][k2] = *(const short8*)(tbse + (OFF)                               \
                                                + ((((ci << 1) + k2)) << 9) + lane8); } }

#define RDP(PFR, SLOT)                                                                     \
    {                                                                                      \
        char* pc = pbase + ((SLOT) << 13);                                                 \
        _Pragma("unroll")                                                                  \
        for (int nj = 0; nj < 4; ++nj) {                                                   \
            PFR[nj][0] = *(const short8*)(pc + PBYTE((nj << 4) + lr, (lg << 3)));          \
            PFR[nj][1] = *(const short8*)(pc + PBYTE((nj << 4) + lr, 32 + (lg << 3)));     \
        }                                                                                  \
    }

#define OMMA(TC, PFR)                                                                      \
    {                                                                                      \
        __builtin_amdgcn_s_setprio(1);                                                     \
        _Pragma("unroll")                                                                  \
        for (int ci = 0; ci < 4; ++ci) {                                                   \
            _Pragma("unroll")                                                              \
            for (int nj = 0; nj < 4; ++nj) {                                               \
                oacc[ci][nj] = MFMA16(TC[ci][0], PFR[nj][0], oacc[ci][nj]);                \
                oacc[ci][nj] = MFMA16(TC[ci][1], PFR[nj][1], oacc[ci][nj]);                \
            }                                                                              \
        }                                                                                  \
        __builtin_amdgcn_s_setprio(0);                                                     \
    }

        // consumer phase: eat tiles t..t+3 from slots S0..S3; pfr dbuf so
        // slot j+1's reads issue under OMMA j. MODE: 2=full reloads, 1=half, 0=none.
#define CPH(S0, S1, S2, S3, MODE)                                                          \
    {                                                                                      \
        short8 pfA[4][2], pfB[4][2];                                                       \
        RDP(pfA, S0); RDP(pfB, S1);                                                        \
        OMMA(tbcA, pfA);                                                                   \
        if ((MODE) >= 1) RLDT(tbcA, 2 * 16384);                                            \
        RDP(pfA, S2);                                                                      \
        OMMA(tbcB, pfB);                                                                   \
        if ((MODE) >= 1) RLDT(tbcB, 3 * 16384);                                            \
        RDP(pfB, S3);                                                                      \
        OMMA(tbcA, pfA);                                                                   \
        if ((MODE) >= 2) RLDT(tbcA, 4 * 16384);                                            \
        OMMA(tbcB, pfB);                                                                   \
        if ((MODE) >= 2) RLDT(tbcB, 5 * 16384);                                            \
        if ((MODE) >= 2) tbse += 4 * 16384;                                                \
        BAR();                                                                             \
    }

        RLDT(tbcA, 0);                  // tile 0
        RLDT(tbcB, 16384);              // tile 1
        f32x4 oacc[4][4];
#pragma unroll
        for (int ci = 0; ci < 4; ++ci)
#pragma unroll
            for (int nj = 0; nj < 4; ++nj) oacc[ci][nj] = zero;
        BAR();

        // phases k=0..13: 7 pairs; k even -> slots 0-3, odd -> 4-7
        for (int pp = 0; pp < 7; ++pp) {
            CPH(0, 1, 2, 3, 2);
            CPH(4, 5, 6, 7, 2);
        }
        CPH(0, 1, 2, 3, 2);    // k=14: tiles 56-59, reloads 58..61
        CPH(4, 5, 6, 7, 1);    // k=15: tiles 60-63, reloads 62,63 only
#undef CPH
#undef OMMA
#undef RDP
#undef RLDT

        // epilogue: write O fp32
#pragma unroll
        for (int ci = 0; ci < 4; ++ci) {
            int c = (cq << 6) + (ci << 4) + (lg << 2);
#pragma unroll
            for (int nj = 0; nj < 4; ++nj) {
                int n = n0 + (nj << 4) + lr;
                float* op = out_b + (size_t)c * 4096 + n;
#pragma unroll
                for (int r = 0; r < 4; ++r) op[(size_t)r * 4096] = oacc[ci][nj][r];
            }
        }
    }
#undef PBYTE
#undef BAR
}

extern "C" void kernel_launch(void* const* d_in, const int* in_sizes, int n_in,
                              void* d_out, int out_size, void* d_ws, size_t ws_size,
                              hipStream_t stream) {
    const float* x = (const float*)d_in[0];     // (4,256,16,16,16) fp32
    const float* W = (const float*)d_in[1];     // (256,256) fp32
    const float* bias = (const float*)d_in[2];  // (256,) fp32
    float* out = (float*)d_out;

    char* ws = (char*)d_ws;
    u16* xff = (u16*)ws;                                   // 8 MiB: xn fragment-major
    u16* tbf = (u16*)(ws + ((size_t)8 << 20));             // 8 MiB: T fragment-major
    u16* Wf = (u16*)(ws + ((size_t)16 << 20));             // 128 KiB: W fragment-major
    float* nrm = (float*)(ws + ((size_t)16 << 20) + (192u << 10));  // 64 KiB

    hipLaunchKernelGGL(k_prep, dim3(256), dim3(256), 0, stream, x, W, xff, Wf, nrm);
    hipLaunchKernelGGL(k_tgemm, dim3(256), dim3(256), 0, stream, Wf, xff, bias, nrm, tbf);
    hipLaunchKernelGGL(k_fused, dim3(256), dim3(512), 0, stream, xff, tbf, out);
}